// Round 5
// baseline (399.658 us; speedup 1.0000x reference)
//
#include <hip/hip_runtime.h>
#include <hip/hip_bf16.h>

#define NN 6144
#define DD 128
#define PBL 136         // padded LDS row stride (bf16 elems) -> balanced banks
#define INV_TAU 10.0f

typedef __attribute__((ext_vector_type(4))) float f32x4;
typedef __attribute__((ext_vector_type(8))) short s16x8;

__device__ __forceinline__ void ld4_async(const float4* p, float4& d) {
    asm volatile("global_load_dwordx4 %0, %1, off" : "=v"(d) : "v"(p));
}
__device__ __forceinline__ void vm_wait0() {
    asm volatile("s_waitcnt vmcnt(0)" ::: "memory");
}

// ---- Kernel 1: L2 normalize -> fp32 Fn, bf16 copies, inv-norms; +W1 prep --
__global__ void k_normalize(const float* __restrict__ embF,
                            const float* __restrict__ embM,
                            const float* __restrict__ embP,
                            const float* __restrict__ W1,
                            float* __restrict__ Fn,
                            float* __restrict__ rnM, float* __restrict__ rnP,
                            __hip_bfloat16* __restrict__ Fnb,
                            __hip_bfloat16* __restrict__ Mnb,
                            __hip_bfloat16* __restrict__ Pnb,
                            __hip_bfloat16* __restrict__ W1tb) {
    int which = blockIdx.y;
    if (which == 3) {                 // W1 (256x128) -> bf16 W1^T (128x256)
        if (blockIdx.x < 128) {
            int n = blockIdx.x, c = threadIdx.x;
            W1tb[n * 256 + c] = __float2bfloat16(W1[c * DD + n]);
        }
        return;
    }
    const float* src = which == 0 ? embF : (which == 1 ? embM : embP);
    __hip_bfloat16* dstb = which == 0 ? Fnb : (which == 1 ? Mnb : Pnb);
    int wave = threadIdx.x >> 6, lane = threadIdx.x & 63;
    int row = blockIdx.x * 4 + wave;
    float2 v = reinterpret_cast<const float2*>(src + (size_t)row * DD)[lane];
    float s = v.x * v.x + v.y * v.y;
#pragma unroll
    for (int m = 1; m <= 32; m <<= 1) s += __shfl_xor(s, m);
    float inv = 1.0f / fmaxf(sqrtf(s), 1e-12f);
    float2 o; o.x = v.x * inv; o.y = v.y * inv;
    if (which == 0)
        reinterpret_cast<float2*>(Fn + (size_t)row * DD)[lane] = o;
    if (lane == 0) {
        if (which == 1) rnM[row] = inv;
        if (which == 2) rnP[row] = inv;
    }
    __hip_bfloat162 ob;
    ob.x = __float2bfloat16(o.x);
    ob.y = __float2bfloat16(o.y);
    reinterpret_cast<__hip_bfloat162*>(dstb + (size_t)row * DD)[lane] = ob;
}

// ------- Kernel 2a: scan+gather, one wave per (row, half). LDS = 1 KB ------
// scan: ballot-compaction of the fp32 adjacency row (24 coalesced dwordx4,
//       8 in flight) -> u16 neighbor list in LDS + exact count. No barriers.
// gather: 4-slot pipelined float2 row loads + fp32 dot + shfl reduce + expf.
// Wave owns the row -> featb/pos/cnt written directly, zero atomics.
__global__ __launch_bounds__(256) void k_scan(
        const float* __restrict__ FM_adj, const float* __restrict__ FP_adj,
        const float* __restrict__ embM, const float* __restrict__ embP,
        const float* __restrict__ Fn,
        const float* __restrict__ rnM, const float* __restrict__ rnP,
        __hip_bfloat16* __restrict__ featb,
        float* __restrict__ FMpos, float* __restrict__ FPpos,
        float* __restrict__ cntF, float* __restrict__ cntP) {
    __shared__ unsigned short listAll[4][128];       // 1 KB total
    const int tid = threadIdx.x, w = tid >> 6, lane = tid & 63;
    unsigned short* listS = listAll[w];
    const int unit = blockIdx.x * 4 + w;             // 0..12287
    const int row = unit >> 1, h = unit & 1;
    const float* adj  = h ? FP_adj : FM_adj;
    const float* embX = h ? embP : embM;
    const float* RN   = h ? rnP : rnM;
    const unsigned long long lt = (1ull << lane) - 1ull;

    float2 f2 = reinterpret_cast<const float2*>(Fn + (size_t)row * DD)[lane];
    const float4* ar = reinterpret_cast<const float4*>(adj + (size_t)row * NN);

    int cnt = 0;
    auto scan4 = [&](const float4& v, int k) {
        unsigned long long b;
        int base = k * 256 + lane * 4;
        b = __ballot(v.x != 0.f);
        if (v.x != 0.f) { int p = cnt + (int)__popcll(b & lt); if (p < 128) listS[p] = (unsigned short)base; }
        cnt += (int)__popcll(b);
        b = __ballot(v.y != 0.f);
        if (v.y != 0.f) { int p = cnt + (int)__popcll(b & lt); if (p < 128) listS[p] = (unsigned short)(base + 1); }
        cnt += (int)__popcll(b);
        b = __ballot(v.z != 0.f);
        if (v.z != 0.f) { int p = cnt + (int)__popcll(b & lt); if (p < 128) listS[p] = (unsigned short)(base + 2); }
        cnt += (int)__popcll(b);
        b = __ballot(v.w != 0.f);
        if (v.w != 0.f) { int p = cnt + (int)__popcll(b & lt); if (p < 128) listS[p] = (unsigned short)(base + 3); }
        cnt += (int)__popcll(b);
    };

    float4 va0 = ar[0 * 64 + lane], va1 = ar[1 * 64 + lane];
    float4 va2 = ar[2 * 64 + lane], va3 = ar[3 * 64 + lane];
    for (int kb = 0; kb < 24; kb += 8) {
        float4 vb0 = ar[(kb + 4) * 64 + lane], vb1 = ar[(kb + 5) * 64 + lane];
        float4 vb2 = ar[(kb + 6) * 64 + lane], vb3 = ar[(kb + 7) * 64 + lane];
        scan4(va0, kb + 0); scan4(va1, kb + 1);
        scan4(va2, kb + 2); scan4(va3, kb + 3);
        if (kb + 8 < 24) {
            va0 = ar[(kb + 8) * 64 + lane];  va1 = ar[(kb + 9) * 64 + lane];
            va2 = ar[(kb + 10) * 64 + lane]; va3 = ar[(kb + 11) * 64 + lane];
        }
        scan4(vb0, kb + 4); scan4(vb1, kb + 5);
        scan4(vb2, kb + 6); scan4(vb3, kb + 7);
    }

    asm volatile("s_waitcnt lgkmcnt(0)" ::: "memory");   // list visible to own wave
    const int K = cnt < 128 ? cnt : 128;
    const float2* ex = reinterpret_cast<const float2*>(embX);
    float2 e0 = {0.f, 0.f}, e1 = {0.f, 0.f}, e2 = {0.f, 0.f}, e3 = {0.f, 0.f};
    float rr0 = 0.f, rr1 = 0.f, rr2 = 0.f, rr3 = 0.f;
#define PREF(i, E, R) if ((i) < K) { int j = listS[(i)]; E = ex[(size_t)j * 64 + lane]; R = RN[j]; }
    PREF(0, e0, rr0) PREF(1, e1, rr1) PREF(2, e2, rr2) PREF(3, e3, rr3)
    float2 racc = {0.f, 0.f};
    float wsum = 0.f;
    for (int kk = 0; kk < K; kk += 4) {
#define STEP(i, E, R)                                                        \
        if (kk + (i) < K) {                                                  \
            float2 ev = E; float rv = R;                                     \
            PREF(kk + (i) + 4, E, R)                                         \
            float d = f2.x * ev.x + f2.y * ev.y;                             \
            d += __shfl_xor(d, 1);  d += __shfl_xor(d, 2);                   \
            d += __shfl_xor(d, 4);  d += __shfl_xor(d, 8);                   \
            d += __shfl_xor(d, 16); d += __shfl_xor(d, 32);                  \
            racc.x += ev.x; racc.y += ev.y;                                  \
            wsum += __expf(d * rv * INV_TAU);                                \
        }
        STEP(0, e0, rr0) STEP(1, e1, rr1) STEP(2, e2, rr2) STEP(3, e3, rr3)
    }
#undef STEP
#undef PREF

    float invK = 1.0f / fmaxf((float)cnt, 1.0f);
    __hip_bfloat162 ob;
    ob.x = __float2bfloat16(racc.x * invK);
    ob.y = __float2bfloat16(racc.y * invK);
    reinterpret_cast<__hip_bfloat162*>(featb + (size_t)row * 256 + h * DD)[lane] = ob;
    if (lane == 0) {
        (h ? FPpos : FMpos)[row] = wsum;
        (h ? cntP : cntF)[row] = (float)cnt;
    }
}

// ------- Kernel 2b: dense exp row-sum over (128-row, 384-col) tiles --------
__global__ __launch_bounds__(256) void k_dense(
        const __hip_bfloat16* __restrict__ Fnb,
        const __hip_bfloat16* __restrict__ Mnb,
        const __hip_bfloat16* __restrict__ Pnb,
        float* __restrict__ FMtot, float* __restrict__ FPtot) {
    __shared__ __hip_bfloat16 Bs[64][PBL];           // 17,408 B
    const int unit = blockIdx.x;
    const int bx = unit % 48, by = (unit / 48) % 16, half = unit / 768;
    const __hip_bfloat16* Bnb = half ? Pnb : Mnb;
    float* TOT = half ? FPtot : FMtot;
    const int tid = threadIdx.x;
    const int w = tid >> 6, lane = tid & 63;
    const int m = lane & 15, q = lane >> 4;
    const int rb = bx * 128 + w * 32;
    const int j0 = by * (NN / 16);                   // 384-col strip

    s16x8 a[2][4];
#pragma unroll
    for (int g = 0; g < 2; ++g)
#pragma unroll
        for (int ks = 0; ks < 4; ++ks)
            a[g][ks] = *reinterpret_cast<const s16x8*>(
                Fnb + (size_t)(rb + g * 16 + m) * DD + ks * 32 + q * 8);

    float4 s0, s1, s2, s3;
    auto issue = [&](int jc) {
        const float4* gp = reinterpret_cast<const float4*>(Bnb + (size_t)jc * DD);
        ld4_async(gp + tid,       s0);
        ld4_async(gp + 256 + tid, s1);
        ld4_async(gp + 512 + tid, s2);
        ld4_async(gp + 768 + tid, s3);
    };
    auto stash = [&](int idx, const float4& v) {
        *reinterpret_cast<float4*>(&Bs[idx >> 4][(idx & 15) * 8]) = v;
    };

    issue(j0);
    float tot[2][4] = {{0.f, 0.f, 0.f, 0.f}, {0.f, 0.f, 0.f, 0.f}};
    for (int it = 0; it < 6; ++it) {
        vm_wait0();
        __syncthreads();
        stash(tid, s0);
        stash(256 + tid, s1);
        stash(512 + tid, s2);
        stash(768 + tid, s3);
        __syncthreads();
        if (it + 1 < 6) issue(j0 + (it + 1) * 64);
#pragma unroll
        for (int t = 0; t < 4; ++t) {
            s16x8 b[4];
#pragma unroll
            for (int ks = 0; ks < 4; ++ks)
                b[ks] = *reinterpret_cast<const s16x8*>(
                    &Bs[t * 16 + m][ks * 32 + q * 8]);
#pragma unroll
            for (int g = 0; g < 2; ++g) {
                f32x4 acc = {0.f, 0.f, 0.f, 0.f};
#pragma unroll
                for (int ks = 0; ks < 4; ++ks)
                    acc = __builtin_amdgcn_mfma_f32_16x16x32_bf16(
                        a[g][ks], b[ks], acc, 0, 0, 0);
#pragma unroll
                for (int r = 0; r < 4; ++r)
                    tot[g][r] += __expf(acc[r] * INV_TAU);
            }
        }
    }
#pragma unroll
    for (int msk = 1; msk <= 8; msk <<= 1)
#pragma unroll
        for (int g = 0; g < 2; ++g)
#pragma unroll
            for (int r = 0; r < 4; ++r)
                tot[g][r] += __shfl_xor(tot[g][r], msk);
    if (m == 0)
#pragma unroll
        for (int g = 0; g < 2; ++g)
#pragma unroll
            for (int r = 0; r < 4; ++r)
                atomicAdd(&TOT[rb + g * 16 + q * 4 + r], tot[g][r]);
}

// ------- Kernel 3: MLP hidden+logit partials via MFMA ----------------------
__global__ __launch_bounds__(256) void k_mlp2(
        const __hip_bfloat16* __restrict__ featb,
        const __hip_bfloat16* __restrict__ W1tb,
        const float* __restrict__ b1, const float* __restrict__ W2,
        float* __restrict__ z) {
    const int tid = threadIdx.x, w = tid >> 6, lane = tid & 63;
    const int m = lane & 15, q = lane >> 4;
    const int unit = blockIdx.x * 4 + w;             // 0..3071
    const int rb = (unit >> 3) * 16, n0 = (unit & 7) * 16;
    f32x4 acc = {0.f, 0.f, 0.f, 0.f};
#pragma unroll
    for (int ks = 0; ks < 8; ++ks) {
        s16x8 a = *reinterpret_cast<const s16x8*>(
            featb + (size_t)(rb + m) * 256 + ks * 32 + q * 8);
        s16x8 b = *reinterpret_cast<const s16x8*>(
            W1tb + (size_t)(n0 + m) * 256 + ks * 32 + q * 8);
        acc = __builtin_amdgcn_mfma_f32_16x16x32_bf16(a, b, acc, 0, 0, 0);
    }
    const int n = n0 + m;
    float bias = b1[n], w20 = W2[2 * n], w21 = W2[2 * n + 1];
#pragma unroll
    for (int r = 0; r < 4; ++r) {
        float h = fmaxf(acc[r] + bias, 0.f);
        float p0 = h * w20, p1 = h * w21;
#pragma unroll
        for (int msk = 1; msk <= 8; msk <<= 1) {
            p0 += __shfl_xor(p0, msk);
            p1 += __shfl_xor(p1, msk);
        }
        if (m == 0) {
            int row = rb + q * 4 + r;
            atomicAdd(&z[2 * row], p0);
            atomicAdd(&z[2 * row + 1], p1);
        }
    }
}

// ------- Kernel 4: softmax weights + loss (one atomic per block) -----------
__global__ void k_loss(const float* __restrict__ z, const float* __restrict__ b2,
                       const float* __restrict__ FMpos, const float* __restrict__ FPpos,
                       const float* __restrict__ FMtot, const float* __restrict__ FPtot,
                       const float* __restrict__ cntF, const float* __restrict__ cntP,
                       float* __restrict__ out) {
    __shared__ float red[4];
    const int tid = threadIdx.x;
    const int lane = tid & 63, wv = tid >> 6;
    const int row = blockIdx.x * 256 + tid;
    float z0 = z[row * 2] + b2[0], z1 = z[row * 2 + 1] + b2[1];
    float mx = fmaxf(z0, z1);
    float e0 = expf(z0 - mx), e1 = expf(z1 - mx);
    float inv = 1.0f / (e0 + e1);
    float w0 = e0 * inv, w1 = e1 * inv;
    out[1 + row * 2 + 0] = w0;
    out[1 + row * 2 + 1] = w1;
    float wp = w0 * FMpos[row] + w1 * FPpos[row];
    float wn = w0 * (FMtot[row] - FMpos[row]) + w1 * (FPtot[row] - FPpos[row]);
    float nei = fmaxf(cntF[row] + cntP[row], 1.0f);
    float ratio = wp / (wp + wn) / nei;
    ratio = fmaxf(ratio, 1e-10f);
    float term = -logf(ratio);
#pragma unroll
    for (int msk = 1; msk <= 32; msk <<= 1) term += __shfl_xor(term, msk);
    if (lane == 0) red[wv] = term;
    __syncthreads();
    if (tid == 0)
        atomicAdd(out, (red[0] + red[1] + red[2] + red[3]) * (1.0f / NN));
}

extern "C" void kernel_launch(void* const* d_in, const int* in_sizes, int n_in,
                              void* d_out, int out_size, void* d_ws, size_t ws_size,
                              hipStream_t stream) {
    const float* embF   = (const float*)d_in[0];
    const float* embM   = (const float*)d_in[1];
    const float* embP   = (const float*)d_in[2];
    const float* FM_adj = (const float*)d_in[3];
    const float* FP_adj = (const float*)d_in[4];
    const float* W1     = (const float*)d_in[5];
    const float* b1     = (const float*)d_in[6];
    const float* W2     = (const float*)d_in[7];
    const float* b2     = (const float*)d_in[8];
    float* out = (float*)d_out;

    float* ws = (float*)d_ws;
    float* FMtot = ws;                       // N  (atomic -> zeroed)
    float* FPtot = FMtot + NN;               // N  (atomic -> zeroed)
    float* zbuf  = FPtot + NN;               // 2N (atomic -> zeroed)
    float* FMpos = zbuf + 2 * NN;            // N
    float* FPpos = FMpos + NN;               // N
    float* cntF  = FPpos + NN;               // N
    float* cntP  = cntF + NN;                // N
    float* rnM   = cntP + NN;                // N
    float* rnP   = rnM + NN;                 // N
    float* Fn    = rnP + NN;                 // N*D fp32 normalized
    __hip_bfloat16* Fnb = (__hip_bfloat16*)(Fn + (size_t)NN * DD);
    __hip_bfloat16* Mnb = Fnb + (size_t)NN * DD;
    __hip_bfloat16* Pnb = Mnb + (size_t)NN * DD;
    __hip_bfloat16* featb = Pnb + (size_t)NN * DD;       // N*256 bf16
    __hip_bfloat16* W1tb  = featb + (size_t)NN * 256;    // 128*256 bf16

    hipMemsetAsync(FMtot, 0, 4 * NN * sizeof(float), stream);
    hipMemsetAsync(d_out, 0, sizeof(float), stream);

    k_normalize<<<dim3(NN / 4, 4), 256, 0, stream>>>(embF, embM, embP, W1,
                                                     Fn, rnM, rnP,
                                                     Fnb, Mnb, Pnb, W1tb);
    k_scan<<<dim3(3072), 256, 0, stream>>>(FM_adj, FP_adj, embM, embP,
                                           Fn, rnM, rnP,
                                           featb, FMpos, FPpos, cntF, cntP);
    k_dense<<<dim3(1536), 256, 0, stream>>>(Fnb, Mnb, Pnb, FMtot, FPtot);
    k_mlp2<<<dim3(768), 256, 0, stream>>>(featb, W1tb, b1, W2, zbuf);
    k_loss<<<dim3(NN / 256), 256, 0, stream>>>(zbuf, b2, FMpos, FPpos,
                                               FMtot, FPtot, cntF, cntP, out);
}

// Round 6
// 360.773 us; speedup vs baseline: 1.1078x; 1.1078x over previous
//
#include <hip/hip_runtime.h>
#include <hip/hip_bf16.h>

#define NN 6144
#define DD 128
#define PBL 136         // padded LDS row stride (bf16 elems) -> balanced banks
#define INV_TAU 10.0f

typedef __attribute__((ext_vector_type(4))) float f32x4;
typedef __attribute__((ext_vector_type(8))) short s16x8;

__device__ __forceinline__ void ld4_async(const float4* p, float4& d) {
    asm volatile("global_load_dwordx4 %0, %1, off" : "=v"(d) : "v"(p));
}
__device__ __forceinline__ void vm_wait0() {
    asm volatile("s_waitcnt vmcnt(0)" ::: "memory");
}

// ---- Kernel 1: L2 normalize -> fp32 Fn, bf16 copies, inv-norms; +W1 prep --
// which==3 also zeroes the atomic buffers (replaces 2 hipMemsetAsync
// dispatches; k_normalize fully precedes k_main in-stream).
__global__ void k_normalize(const float* __restrict__ embF,
                            const float* __restrict__ embM,
                            const float* __restrict__ embP,
                            const float* __restrict__ W1,
                            float* __restrict__ Fn,
                            float* __restrict__ rnM, float* __restrict__ rnP,
                            __hip_bfloat16* __restrict__ Fnb,
                            __hip_bfloat16* __restrict__ Mnb,
                            __hip_bfloat16* __restrict__ Pnb,
                            __hip_bfloat16* __restrict__ W1tb,
                            float* __restrict__ FMtot,   // 2N contiguous f32
                            float* __restrict__ out) {
    int which = blockIdx.y;
    if (which == 3) {
        if (blockIdx.x < 128) {       // W1 (256x128) -> bf16 W1^T (128x256)
            int n = blockIdx.x, c = threadIdx.x;
            W1tb[n * 256 + c] = __float2bfloat16(W1[c * DD + n]);
        } else if (blockIdx.x < 176) {           // zero FMtot+FPtot (2N)
            int i = (blockIdx.x - 128) * 256 + threadIdx.x;
            FMtot[i] = 0.f;
        } else if (blockIdx.x == 176 && threadIdx.x == 0) {
            out[0] = 0.f;                        // zero loss accumulator
        }
        return;
    }
    const float* src = which == 0 ? embF : (which == 1 ? embM : embP);
    __hip_bfloat16* dstb = which == 0 ? Fnb : (which == 1 ? Mnb : Pnb);
    int wave = threadIdx.x >> 6, lane = threadIdx.x & 63;
    int row = blockIdx.x * 4 + wave;
    float2 v = reinterpret_cast<const float2*>(src + (size_t)row * DD)[lane];
    float s = v.x * v.x + v.y * v.y;
#pragma unroll
    for (int m = 1; m <= 32; m <<= 1) s += __shfl_xor(s, m);
    float inv = 1.0f / fmaxf(sqrtf(s), 1e-12f);
    float2 o; o.x = v.x * inv; o.y = v.y * inv;
    if (which == 0)
        reinterpret_cast<float2*>(Fn + (size_t)row * DD)[lane] = o;
    if (lane == 0) {
        if (which == 1) rnM[row] = inv;
        if (which == 2) rnP[row] = inv;
    }
    __hip_bfloat162 ob;
    ob.x = __float2bfloat16(o.x);
    ob.y = __float2bfloat16(o.y);
    reinterpret_cast<__hip_bfloat162*>(dstb + (size_t)row * DD)[lane] = ob;
}

// ---------- sparse body: fused scan + gather for one (row, half) -----------
__device__ __forceinline__ void sparse_body(
        int unit, char* smem,
        const float* __restrict__ FM_adj, const float* __restrict__ FP_adj,
        const float* __restrict__ embM, const float* __restrict__ embP,
        const float* __restrict__ Fn,
        const float* __restrict__ rnM, const float* __restrict__ rnP,
        __hip_bfloat16* __restrict__ featb,
        float* __restrict__ FMpos, float* __restrict__ FPpos,
        float* __restrict__ cntF, float* __restrict__ cntP) {
    float* FnS = (float*)smem;                         // 128 f
    int (*lbufT)[5] = (int(*)[5])(smem + 512);         // 256x5 i (stride 5: banks)
    int* listS = (int*)(smem + 512 + 5120);            // 128 i
    float (*reprS)[DD] = (float(*)[DD])(smem + 512 + 5120 + 512);  // 8x128 f
    float* posS = (float*)(smem + 512 + 5120 + 512 + 4096);        // 8 f
    int* wvS = (int*)(smem + 512 + 5120 + 512 + 4096 + 32);        // 4 i
    int* Ktot = (int*)(smem + 512 + 5120 + 512 + 4096 + 32 + 16);  // 2 i

    const int row = unit >> 1, h = unit & 1;
    const float* adj  = h ? FP_adj : FM_adj;
    const float* embX = h ? embP : embM;
    const float* RN   = h ? rnP : rnM;
    const int tid = threadIdx.x, wv = tid >> 6, lane = tid & 63;

    if (tid < 32)
        reinterpret_cast<float4*>(FnS)[tid] =
            reinterpret_cast<const float4*>(Fn + (size_t)row * DD)[tid];

    // ---- phase A: scan with 6 asm-forced loads in flight ----
    const float4* rp = reinterpret_cast<const float4*>(adj + (size_t)row * NN);
    float4 v0, v1, v2, v3, v4, v5;
    ld4_async(rp + tid,        v0);
    ld4_async(rp + 256 + tid,  v1);
    ld4_async(rp + 512 + tid,  v2);
    ld4_async(rp + 768 + tid,  v3);
    ld4_async(rp + 1024 + tid, v4);
    ld4_async(rp + 1280 + tid, v5);
    vm_wait0();
    float4 vv[6] = {v0, v1, v2, v3, v4, v5};
    int mycnt = 0;
#pragma unroll
    for (int u = 0; u < 6; ++u) {
        int cb = (u * 256 + tid) * 4;
        if (vv[u].x != 0.f) { if (mycnt < 4) lbufT[tid][mycnt] = cb;     mycnt++; }
        if (vv[u].y != 0.f) { if (mycnt < 4) lbufT[tid][mycnt] = cb + 1; mycnt++; }
        if (vv[u].z != 0.f) { if (mycnt < 4) lbufT[tid][mycnt] = cb + 2; mycnt++; }
        if (vv[u].w != 0.f) { if (mycnt < 4) lbufT[tid][mycnt] = cb + 3; mycnt++; }
    }
    int cnt = mycnt < 4 ? mycnt : 4;         // P(thread>4 nnz in 24 cols) ~ 0
    int x = cnt;                             // inclusive prefix within wave
#pragma unroll
    for (int d = 1; d < 64; d <<= 1) {
        int y = __shfl_up(x, d);
        if (lane >= d) x += y;
    }
    int t = mycnt;                           // true per-wave total
#pragma unroll
    for (int msk = 1; msk <= 32; msk <<= 1) t += __shfl_xor(t, msk);
    if (tid == 0) Ktot[1] = 0;
    if (lane == 63) wvS[wv] = x;
    __syncthreads();
    if (lane == 0) atomicAdd(&Ktot[1], t);
    if (tid == 0) {
        int s = 0;
#pragma unroll
        for (int i = 0; i < 4; ++i) { int v = wvS[i]; wvS[i] = s; s += v; }
        Ktot[0] = s < 128 ? s : 128;
    }
    __syncthreads();
    int off = wvS[wv] + (x - cnt);
    for (int i = 0; i < cnt; ++i) {
        int s = off + i;
        if (s < 128) listS[s] = lbufT[tid][i];
    }
    __syncthreads();
    const int K = Ktot[0];
    const float trueK = (float)Ktot[1];

    // ---- phase B: gather (half-wave per neighbor) ----
    const int hw = tid >> 5, sl = tid & 31;
    float4 f4 = reinterpret_cast<const float4*>(FnS)[sl];
    float4 racc = {0.f, 0.f, 0.f, 0.f};
    float wsum = 0.f;
    for (int k = hw; k < K; k += 8) {
        int j = listS[k];
        float rn = RN[j];
        float4 e = reinterpret_cast<const float4*>(embX + (size_t)j * DD)[sl];
        racc.x += e.x; racc.y += e.y; racc.z += e.z; racc.w += e.w;
        float d = f4.x * e.x + f4.y * e.y + f4.z * e.z + f4.w * e.w;
#pragma unroll
        for (int msk = 1; msk <= 16; msk <<= 1) d += __shfl_xor(d, msk);
        wsum += __expf(d * rn * INV_TAU);
    }
    reinterpret_cast<float4*>(&reprS[hw][0])[sl] = racc;
    if (sl == 0) posS[hw] = wsum;
    __syncthreads();
    if (tid < DD) {
        float s = 0.f;
#pragma unroll
        for (int i = 0; i < 8; ++i) s += reprS[i][tid];
        featb[(size_t)row * (2 * DD) + h * DD + tid] =
            __float2bfloat16(s / fmaxf(trueK, 1.0f));
    }
    if (tid == 0) {
        float p = 0.f;
#pragma unroll
        for (int i = 0; i < 8; ++i) p += posS[i];
        (h ? FPpos : FMpos)[row] = p;
        (h ? cntP : cntF)[row] = trueK;
    }
}

// ---------- dense body: exp row-sum over one (128-row, 384-col) tile -------
__device__ __forceinline__ void dense_body(
        int unit, char* smem,
        const __hip_bfloat16* __restrict__ Fnb,
        const __hip_bfloat16* __restrict__ Mnb,
        const __hip_bfloat16* __restrict__ Pnb,
        float* __restrict__ FMtot, float* __restrict__ FPtot) {
    __hip_bfloat16 (*Bs)[PBL] = (__hip_bfloat16(*)[PBL])smem;   // 64 x PBL
    const int bx = unit % 48, by = (unit / 48) % 16, half = unit / 768;
    const __hip_bfloat16* Bnb = half ? Pnb : Mnb;
    float* TOT = half ? FPtot : FMtot;
    const int tid = threadIdx.x;
    const int w = tid >> 6, lane = tid & 63;
    const int m = lane & 15, q = lane >> 4;
    const int rb = bx * 128 + w * 32;
    const int j0 = by * (NN / 16);                   // 384-col strip

    s16x8 a[2][4];
#pragma unroll
    for (int g = 0; g < 2; ++g)
#pragma unroll
        for (int ks = 0; ks < 4; ++ks)
            a[g][ks] = *reinterpret_cast<const s16x8*>(
                Fnb + (size_t)(rb + g * 16 + m) * DD + ks * 32 + q * 8);

    float4 s0, s1, s2, s3;
    auto issue = [&](int jc) {
        const float4* gp = reinterpret_cast<const float4*>(Bnb + (size_t)jc * DD);
        ld4_async(gp + tid,       s0);
        ld4_async(gp + 256 + tid, s1);
        ld4_async(gp + 512 + tid, s2);
        ld4_async(gp + 768 + tid, s3);
    };
    auto stash = [&](int idx, const float4& v) {
        *reinterpret_cast<float4*>(&Bs[idx >> 4][(idx & 15) * 8]) = v;
    };

    issue(j0);
    float tot[2][4] = {{0.f, 0.f, 0.f, 0.f}, {0.f, 0.f, 0.f, 0.f}};
    for (int it = 0; it < 6; ++it) {
        vm_wait0();
        __syncthreads();
        stash(tid, s0);
        stash(256 + tid, s1);
        stash(512 + tid, s2);
        stash(768 + tid, s3);
        __syncthreads();
        if (it + 1 < 6) issue(j0 + (it + 1) * 64);
#pragma unroll
        for (int t = 0; t < 4; ++t) {
            s16x8 b[4];
#pragma unroll
            for (int ks = 0; ks < 4; ++ks)
                b[ks] = *reinterpret_cast<const s16x8*>(
                    &Bs[t * 16 + m][ks * 32 + q * 8]);
#pragma unroll
            for (int g = 0; g < 2; ++g) {
                f32x4 acc = {0.f, 0.f, 0.f, 0.f};
#pragma unroll
                for (int ks = 0; ks < 4; ++ks)
                    acc = __builtin_amdgcn_mfma_f32_16x16x32_bf16(
                        a[g][ks], b[ks], acc, 0, 0, 0);
#pragma unroll
                for (int r = 0; r < 4; ++r)
                    tot[g][r] += __expf(acc[r] * INV_TAU);
            }
        }
    }
#pragma unroll
    for (int msk = 1; msk <= 8; msk <<= 1)
#pragma unroll
        for (int g = 0; g < 2; ++g)
#pragma unroll
            for (int r = 0; r < 4; ++r)
                tot[g][r] += __shfl_xor(tot[g][r], msk);
    if (m == 0)
#pragma unroll
        for (int g = 0; g < 2; ++g)
#pragma unroll
            for (int r = 0; r < 4; ++r)
                atomicAdd(&TOT[rb + g * 16 + q * 4 + r], tot[g][r]);
}

// ------- Kernel 2: co-scheduled sparse-stream + dense-MFMA -----------------
__global__ __launch_bounds__(256) void k_main(
        const float* __restrict__ FM_adj, const float* __restrict__ FP_adj,
        const float* __restrict__ embM, const float* __restrict__ embP,
        const float* __restrict__ Fn,
        const float* __restrict__ rnM, const float* __restrict__ rnP,
        const __hip_bfloat16* __restrict__ Fnb,
        const __hip_bfloat16* __restrict__ Mnb,
        const __hip_bfloat16* __restrict__ Pnb,
        __hip_bfloat16* __restrict__ featb,
        float* __restrict__ FMpos, float* __restrict__ FPpos,
        float* __restrict__ FMtot, float* __restrict__ FPtot,
        float* __restrict__ cntF, float* __restrict__ cntP) {
    __shared__ char smem[64 * PBL * 2];              // 17408 B (union)
    const int b = blockIdx.x;
    const int u = b / 9, r = b - u * 9;
    if (r == 8)
        dense_body(u, smem, Fnb, Mnb, Pnb, FMtot, FPtot);
    else
        sparse_body(u * 8 + r, smem, FM_adj, FP_adj, embM, embP,
                    Fn, rnM, rnP, featb, FMpos, FPpos, cntF, cntP);
}

// ------- Kernel 3: fused MLP + softmax weights + loss ----------------------
// one block per 16 rows: each wave computes 2 n-columns (32 hidden units),
// z reduced across waves in LDS, softmax+loss in-block. Replaces
// k_mlp2 + k_loss (one fewer dispatch; no zbuf global round-trip).
__global__ __launch_bounds__(256) void k_post(
        const __hip_bfloat16* __restrict__ featb,
        const __hip_bfloat16* __restrict__ W1tb,
        const float* __restrict__ b1, const float* __restrict__ W2,
        const float* __restrict__ b2,
        const float* __restrict__ FMpos, const float* __restrict__ FPpos,
        const float* __restrict__ FMtot, const float* __restrict__ FPtot,
        const float* __restrict__ cntF, const float* __restrict__ cntP,
        float* __restrict__ out) {
    __shared__ float zred[4][16][2];
    const int tid = threadIdx.x, w = tid >> 6, lane = tid & 63;
    const int m = lane & 15, q = lane >> 4;
    const int rb = blockIdx.x * 16;
    const int n0a = w * 32, n0b = w * 32 + 16;
    f32x4 accA = {0.f, 0.f, 0.f, 0.f}, accB = {0.f, 0.f, 0.f, 0.f};
#pragma unroll
    for (int ks = 0; ks < 8; ++ks) {
        s16x8 a = *reinterpret_cast<const s16x8*>(
            featb + (size_t)(rb + m) * 256 + ks * 32 + q * 8);
        s16x8 bA = *reinterpret_cast<const s16x8*>(
            W1tb + (size_t)(n0a + m) * 256 + ks * 32 + q * 8);
        s16x8 bB = *reinterpret_cast<const s16x8*>(
            W1tb + (size_t)(n0b + m) * 256 + ks * 32 + q * 8);
        accA = __builtin_amdgcn_mfma_f32_16x16x32_bf16(a, bA, accA, 0, 0, 0);
        accB = __builtin_amdgcn_mfma_f32_16x16x32_bf16(a, bB, accB, 0, 0, 0);
    }
    const float biasA = b1[n0a + m], biasB = b1[n0b + m];
    const float wA0 = W2[2 * (n0a + m)], wA1 = W2[2 * (n0a + m) + 1];
    const float wB0 = W2[2 * (n0b + m)], wB1 = W2[2 * (n0b + m) + 1];
#pragma unroll
    for (int r = 0; r < 4; ++r) {
        float hA = fmaxf(accA[r] + biasA, 0.f);
        float hB = fmaxf(accB[r] + biasB, 0.f);
        float p0 = hA * wA0 + hB * wB0;
        float p1 = hA * wA1 + hB * wB1;
#pragma unroll
        for (int msk = 1; msk <= 8; msk <<= 1) {
            p0 += __shfl_xor(p0, msk);
            p1 += __shfl_xor(p1, msk);
        }
        if (m == 0) {
            zred[w][q * 4 + r][0] = p0;
            zred[w][q * 4 + r][1] = p1;
        }
    }
    __syncthreads();
    if (tid < 16) {
        const int row = rb + tid;
        float z0 = zred[0][tid][0] + zred[1][tid][0]
                 + zred[2][tid][0] + zred[3][tid][0] + b2[0];
        float z1 = zred[0][tid][1] + zred[1][tid][1]
                 + zred[2][tid][1] + zred[3][tid][1] + b2[1];
        float mx = fmaxf(z0, z1);
        float e0 = expf(z0 - mx), e1 = expf(z1 - mx);
        float inv = 1.0f / (e0 + e1);
        float w0 = e0 * inv, w1 = e1 * inv;
        out[1 + row * 2 + 0] = w0;
        out[1 + row * 2 + 1] = w1;
        float wp = w0 * FMpos[row] + w1 * FPpos[row];
        float wn = w0 * (FMtot[row] - FMpos[row]) + w1 * (FPtot[row] - FPpos[row]);
        float nei = fmaxf(cntF[row] + cntP[row], 1.0f);
        float ratio = fmaxf(wp / (wp + wn) / nei, 1e-10f);
        float term = -logf(ratio);
#pragma unroll
        for (int msk = 1; msk <= 8; msk <<= 1) term += __shfl_xor(term, msk);
        if (tid == 0) atomicAdd(out, term * (1.0f / NN));
    }
}

extern "C" void kernel_launch(void* const* d_in, const int* in_sizes, int n_in,
                              void* d_out, int out_size, void* d_ws, size_t ws_size,
                              hipStream_t stream) {
    const float* embF   = (const float*)d_in[0];
    const float* embM   = (const float*)d_in[1];
    const float* embP   = (const float*)d_in[2];
    const float* FM_adj = (const float*)d_in[3];
    const float* FP_adj = (const float*)d_in[4];
    const float* W1     = (const float*)d_in[5];
    const float* b1     = (const float*)d_in[6];
    const float* W2     = (const float*)d_in[7];
    const float* b2     = (const float*)d_in[8];
    float* out = (float*)d_out;

    float* ws = (float*)d_ws;
    float* FMtot = ws;                       // N  (atomic -> zeroed in k_normalize)
    float* FPtot = FMtot + NN;               // N  (atomic -> zeroed in k_normalize)
    float* zbuf  = FPtot + NN;               // 2N (unused; layout kept)
    float* FMpos = zbuf + 2 * NN;            // N
    float* FPpos = FMpos + NN;               // N
    float* cntF  = FPpos + NN;               // N
    float* cntP  = cntF + NN;                // N
    float* rnM   = cntP + NN;                // N
    float* rnP   = rnM + NN;                 // N
    float* Fn    = rnP + NN;                 // N*D fp32 normalized
    __hip_bfloat16* Fnb = (__hip_bfloat16*)(Fn + (size_t)NN * DD);
    __hip_bfloat16* Mnb = Fnb + (size_t)NN * DD;
    __hip_bfloat16* Pnb = Mnb + (size_t)NN * DD;
    __hip_bfloat16* featb = Pnb + (size_t)NN * DD;       // N*256 bf16
    __hip_bfloat16* W1tb  = featb + (size_t)NN * 256;    // 128*256 bf16

    k_normalize<<<dim3(NN / 4, 4), 256, 0, stream>>>(embF, embM, embP, W1,
                                                     Fn, rnM, rnP,
                                                     Fnb, Mnb, Pnb, W1tb,
                                                     FMtot, out);
    k_main<<<dim3(13824), 256, 0, stream>>>(FM_adj, FP_adj, embM, embP,
                                            Fn, rnM, rnP, Fnb, Mnb, Pnb,
                                            featb, FMpos, FPpos, FMtot, FPtot,
                                            cntF, cntP);
    k_post<<<dim3(NN / 16), 256, 0, stream>>>(featb, W1tb, b1, W2, b2,
                                              FMpos, FPpos, FMtot, FPtot,
                                              cntF, cntP, out);
}